// Round 1
// baseline (860.457 us; speedup 1.0000x reference)
//
#include <hip/hip_runtime.h>

#define NNODES 50000
#define NEDGES 1600000

__device__ __forceinline__ float leaky02(float x) { return x > 0.f ? x : 0.2f * x; }

// ---------------- CSR build (dst-sorted) ----------------
__global__ void k_hist(const int* __restrict__ dst, int* __restrict__ deg, int E) {
  int e = blockIdx.x * blockDim.x + threadIdx.x;
  if (e < E) atomicAdd(&deg[dst[e]], 1);
}

__global__ void k_scan1(const int* __restrict__ deg, int* __restrict__ offs,
                        int* __restrict__ partial, int n) {
  __shared__ int sh[256];
  int t = threadIdx.x;
  int i = blockIdx.x * 256 + t;
  int v = (i < n) ? deg[i] : 0;
  sh[t] = v;
  __syncthreads();
  for (int d = 1; d < 256; d <<= 1) {
    int u = (t >= d) ? sh[t - d] : 0;
    __syncthreads();
    sh[t] += u;
    __syncthreads();
  }
  if (i < n) offs[i] = sh[t] - v;  // exclusive within block
  if (t == 255) partial[blockIdx.x] = sh[255];
}

__global__ void k_scan2(int* __restrict__ partial, int nb) {
  __shared__ int sh[256];
  int t = threadIdx.x;
  int v = (t < nb) ? partial[t] : 0;
  sh[t] = v;
  __syncthreads();
  for (int d = 1; d < 256; d <<= 1) {
    int u = (t >= d) ? sh[t - d] : 0;
    __syncthreads();
    sh[t] += u;
    __syncthreads();
  }
  if (t < nb) partial[t] = sh[t] - v;  // exclusive block offsets
}

__global__ void k_scan3(int* __restrict__ offs, int* __restrict__ cursor,
                        const int* __restrict__ partial, int n) {
  int i = blockIdx.x * 256 + threadIdx.x;
  if (i < n) {
    int o = offs[i] + partial[blockIdx.x];
    offs[i] = o;
    cursor[i] = o;
  }
}

__global__ void k_scatter(const int* __restrict__ src, const int* __restrict__ dst,
                          int* __restrict__ cursor, int* __restrict__ csr, int E) {
  int e = blockIdx.x * blockDim.x + threadIdx.x;
  if (e < E) {
    int d = dst[e];
    int pos = atomicAdd(&cursor[d], 1);
    csr[pos] = src[e];
  }
}

// ---------------- Tiled GEMM: 64 rows x NC cols per block ----------------
// A [M,K] row-major (optionally BN+ReLU transformed on the fly),
// B0 [K,SPLIT] (+bias0 on out0), B1 [K,NC-SPLIT] (no bias, out1).
template <int K, int KC, int NC, int TN, int SPLIT, bool BN>
__global__ __launch_bounds__(256) void k_gemm(
    const float* __restrict__ A, const float* __restrict__ scale,
    const float* __restrict__ shift, const float* __restrict__ B0,
    const float* __restrict__ B1, const float* __restrict__ bias0,
    float* __restrict__ out0, float* __restrict__ out1, int M) {
  __shared__ float As[KC][68];   // k-major, padded
  __shared__ float Bs[KC][NC];
  const int tid = threadIdx.x;
  const int row0 = blockIdx.x * 64;
  const int rg = tid & 15;    // 16 row-groups of 4 rows
  const int cg = tid >> 4;    // 16 col-groups of TN cols

  float acc[4][TN];
#pragma unroll
  for (int r = 0; r < 4; ++r)
#pragma unroll
    for (int j = 0; j < TN; ++j) acc[r][j] = 0.f;

  for (int k0 = 0; k0 < K; k0 += KC) {
    // stage A (transposed into LDS), applying BN+ReLU if requested
    constexpr int AF4 = KC / 16;  // float4 loads per thread
#pragma unroll
    for (int r = 0; r < AF4; ++r) {
      int idx = tid + r * 256;
      int row = idx / (KC / 4);
      int kb = idx % (KC / 4);
      float4 v = make_float4(0.f, 0.f, 0.f, 0.f);
      int grow = row0 + row;
      if (grow < M) {
        v = *reinterpret_cast<const float4*>(&A[(size_t)grow * K + k0 + kb * 4]);
        if (BN) {
          int kb4 = k0 + kb * 4;
          float4 sc = *reinterpret_cast<const float4*>(&scale[kb4]);
          float4 sf = *reinterpret_cast<const float4*>(&shift[kb4]);
          v.x = fmaxf(v.x * sc.x + sf.x, 0.f);
          v.y = fmaxf(v.y * sc.y + sf.y, 0.f);
          v.z = fmaxf(v.z * sc.z + sf.z, 0.f);
          v.w = fmaxf(v.w * sc.w + sf.w, 0.f);
        }
      }
      As[kb * 4 + 0][row] = v.x;
      As[kb * 4 + 1][row] = v.y;
      As[kb * 4 + 2][row] = v.z;
      As[kb * 4 + 3][row] = v.w;
    }
    // stage B
    constexpr int NB0 = KC * SPLIT / 256;
#pragma unroll
    for (int r = 0; r < NB0; ++r) {
      int idx = tid + r * 256;
      int kk = idx / SPLIT;
      int c = idx % SPLIT;
      Bs[kk][c] = B0[(size_t)(k0 + kk) * SPLIT + c];
    }
    if constexpr (NC > SPLIT) {
      constexpr int W1 = NC - SPLIT;
      constexpr int NB1 = KC * W1 / 256;
#pragma unroll
      for (int r = 0; r < NB1; ++r) {
        int idx = tid + r * 256;
        int kk = idx / W1;
        int c = idx % W1;
        Bs[kk][SPLIT + c] = B1[(size_t)(k0 + kk) * W1 + c];
      }
    }
    __syncthreads();
#pragma unroll
    for (int kk = 0; kk < KC; ++kk) {
      float4 a4 = *reinterpret_cast<const float4*>(&As[kk][rg * 4]);
      float av[4] = {a4.x, a4.y, a4.z, a4.w};
      float bv[TN];
#pragma unroll
      for (int j = 0; j < TN; ++j) bv[j] = Bs[kk][cg * TN + j];
#pragma unroll
      for (int r = 0; r < 4; ++r)
#pragma unroll
        for (int j = 0; j < TN; ++j) acc[r][j] += av[r] * bv[j];
    }
    __syncthreads();
  }
  // epilogue
#pragma unroll
  for (int r = 0; r < 4; ++r) {
    int row = row0 + rg * 4 + r;
    if (row < M) {
#pragma unroll
      for (int j = 0; j < TN; ++j) {
        int c = cg * TN + j;
        float v = acc[r][j];
        if (c < SPLIT)
          out0[(size_t)row * SPLIT + c] = v + bias0[c];
        else
          out1[(size_t)row * (NC - SPLIT) + (c - SPLIT)] = v;
      }
    }
  }
}

// ---------------- per-row attention scalars s = g.as, d = g.ad ----------------
__global__ __launch_bounds__(256) void k_sdot(const float* __restrict__ g,
                                              const float* __restrict__ as_,
                                              const float* __restrict__ ad_,
                                              float* __restrict__ sv,
                                              float* __restrict__ dv, int N) {
  int lane = threadIdx.x & 31;
  int row = blockIdx.x * 8 + (threadIdx.x >> 5);
  if (row >= N) return;
  float v = g[(size_t)row * 32 + lane];
  float a = v * as_[lane];
  float b = v * ad_[lane];
#pragma unroll
  for (int w = 16; w >= 1; w >>= 1) {
    a += __shfl_xor(a, w);
    b += __shfl_xor(b, w);
  }
  if (lane == 0) {
    sv[row] = a;
    dv[row] = b;
  }
}

// ---------------- GAT aggregation (half-wave per dst node, CSR + self-loop) ----------------
__global__ __launch_bounds__(256) void k_gat_agg(
    const float* __restrict__ h, const float* __restrict__ sv,
    const float* __restrict__ dv, const int* __restrict__ offs,
    const int* __restrict__ deg, const int* __restrict__ csr,
    const float* __restrict__ bias, float* __restrict__ out, int N) {
  int lane = threadIdx.x & 31;
  int node = blockIdx.x * 8 + (threadIdx.x >> 5);
  if (node >= N) return;
  int start = offs[node];
  int cnt = deg[node];
  float di = dv[node];
  float es = leaky02(sv[node] + di);  // self-loop logit
  // pass 1: max over incoming edges (lanes stride edges)
  float m = es;
  for (int k = lane; k < cnt; k += 32) {
    int j = csr[start + k];
    m = fmaxf(m, leaky02(sv[j] + di));
  }
#pragma unroll
  for (int w = 16; w >= 1; w >>= 1) m = fmaxf(m, __shfl_xor(m, w));
  // pass 2: lane = channel; serial over edges
  float ex0 = __expf(es - m);
  float den = ex0;
  float acc = ex0 * h[(size_t)node * 32 + lane];
  for (int k = 0; k < cnt; ++k) {
    int j = csr[start + k];
    float ex = __expf(leaky02(sv[j] + di) - m);
    den += ex;
    acc += ex * h[(size_t)j * 32 + lane];
  }
  out[(size_t)node * 32 + lane] = fmaxf(acc / den + bias[lane], 0.f);
}

// ---------------- small 32x32 GEMM (h1 @ W_g2) fused with s2/d2 ----------------
__global__ __launch_bounds__(256) void k_small_gemm_sd(
    const float* __restrict__ hin, const float* __restrict__ W,
    const float* __restrict__ as_, const float* __restrict__ ad_,
    float* __restrict__ gout, float* __restrict__ sv, float* __restrict__ dv,
    int N) {
  __shared__ float Ws[32][32];
  {
    int t = threadIdx.x;
#pragma unroll
    for (int r = 0; r < 4; ++r) {
      int idx = t + r * 256;
      Ws[idx >> 5][idx & 31] = W[idx];
    }
  }
  __syncthreads();
  int lane = threadIdx.x & 31;
  int row = blockIdx.x * 8 + (threadIdx.x >> 5);
  if (row >= N) return;
  float hv = hin[(size_t)row * 32 + lane];
  float acc = 0.f;
#pragma unroll
  for (int k = 0; k < 32; ++k) acc += __shfl(hv, k, 32) * Ws[k][lane];
  gout[(size_t)row * 32 + lane] = acc;
  float a = acc * as_[lane];
  float b = acc * ad_[lane];
#pragma unroll
  for (int w = 16; w >= 1; w >>= 1) {
    a += __shfl_xor(a, w);
    b += __shfl_xor(b, w);
  }
  if (lane == 0) {
    sv[row] = a;
    dv[row] = b;
  }
}

// ---------------- column stats (sum, sumsq) for BatchNorm ----------------
template <int NC>
__global__ __launch_bounds__(256) void k_colstats(const float* __restrict__ a, int M,
                                                  float* __restrict__ sum,
                                                  float* __restrict__ sumsq) {
  constexpr int RG = 256 / NC;
  __shared__ float sh[2][256];
  int col = threadIdx.x % NC;
  int rg = threadIdx.x / NC;
  float s = 0.f, q = 0.f;
  for (int r = blockIdx.x * RG + rg; r < M; r += gridDim.x * RG) {
    float v = a[(size_t)r * NC + col];
    s += v;
    q += v * v;
  }
  sh[0][threadIdx.x] = s;
  sh[1][threadIdx.x] = q;
  __syncthreads();
  if (rg == 0) {
#pragma unroll
    for (int g = 1; g < RG; ++g) {
      s += sh[0][col + g * NC];
      q += sh[1][col + g * NC];
    }
    atomicAdd(&sum[col], s);
    atomicAdd(&sumsq[col], q);
  }
}

__global__ void k_finalize(const float* __restrict__ sum, const float* __restrict__ sumsq,
                           const float* __restrict__ gamma, const float* __restrict__ beta,
                           float* __restrict__ scale, float* __restrict__ shift, int NC,
                           float invM) {
  int c = threadIdx.x;
  if (c < NC) {
    float mean = sum[c] * invM;
    float var = sumsq[c] * invM - mean * mean;  // biased, matches jnp.var
    float rs = rsqrtf(var + 1e-5f);
    float sc = rs * gamma[c];
    scale[c] = sc;
    shift[c] = beta[c] - mean * sc;
  }
}

// ---------------- final: BN3+ReLU, h2@W_gf+b_gf, blend, @W_f+b_f, ReLU ----------------
__global__ __launch_bounds__(256) void k_final(
    const float* __restrict__ mlp3, const float* __restrict__ sc3,
    const float* __restrict__ sh3, const float* __restrict__ h2,
    const float* __restrict__ Wgf, const float* __restrict__ bgf,
    const float* __restrict__ Wf, const float* __restrict__ bf,
    float* __restrict__ out, int N) {
  __shared__ float WfS[32 * 256];
  __shared__ float WgfS[32][32];
  __shared__ float bgfS[32], sc3S[32], sh3S[32];
  int t = threadIdx.x;
#pragma unroll
  for (int r = 0; r < 32; ++r) WfS[t + r * 256] = Wf[t + r * 256];
#pragma unroll
  for (int r = 0; r < 4; ++r) {
    int idx = t + r * 256;
    WgfS[idx >> 5][idx & 31] = Wgf[idx];
  }
  if (t < 32) {
    bgfS[t] = bgf[t];
    sc3S[t] = sc3[t];
    sh3S[t] = sh3[t];
  }
  __syncthreads();
  int wv = t >> 6, lane = t & 63;
  const float4* Wf4 = reinterpret_cast<const float4*>(WfS);
  float4 bias = reinterpret_cast<const float4*>(bf)[lane];
  for (int it = 0; it < 4; ++it) {
    int row = blockIdx.x * 16 + wv * 4 + it;
    float bl = 0.f;
    if (lane < 32) {
      float h2v = h2[(size_t)row * 32 + lane];
      float a = bgfS[lane];
#pragma unroll
      for (int k = 0; k < 32; ++k) a += __shfl(h2v, k, 32) * WgfS[k][lane];
      float pre = mlp3[(size_t)row * 32 + lane];
      float rv = fmaxf(pre * sc3S[lane] + sh3S[lane], 0.f);
      bl = 0.5f * rv + 0.5f * a;
    }
    float4 o = bias;
#pragma unroll
    for (int k = 0; k < 32; ++k) {
      float b = __shfl(bl, k);  // broadcast from lanes 0..31
      float4 w = Wf4[k * 64 + lane];
      o.x += b * w.x;
      o.y += b * w.y;
      o.z += b * w.z;
      o.w += b * w.w;
    }
    o.x = fmaxf(o.x, 0.f);
    o.y = fmaxf(o.y, 0.f);
    o.z = fmaxf(o.z, 0.f);
    o.w = fmaxf(o.w, 0.f);
    reinterpret_cast<float4*>(out)[(size_t)row * 64 + lane] = o;
  }
}

extern "C" void kernel_launch(void* const* d_in, const int* in_sizes, int n_in,
                              void* d_out, int out_size, void* d_ws, size_t ws_size,
                              hipStream_t stream) {
  const float* x = (const float*)d_in[0];
  const int* edge = (const int*)d_in[1];
  const float* W_g1 = (const float*)d_in[2];
  const float* as_g1 = (const float*)d_in[3];
  const float* ad_g1 = (const float*)d_in[4];
  const float* b_g1 = (const float*)d_in[5];
  const float* W_g2 = (const float*)d_in[6];
  const float* as_g2 = (const float*)d_in[7];
  const float* ad_g2 = (const float*)d_in[8];
  const float* b_g2 = (const float*)d_in[9];
  const float* W_gf = (const float*)d_in[10];
  const float* b_gf = (const float*)d_in[11];
  const float* W_m1 = (const float*)d_in[12];
  const float* b_m1 = (const float*)d_in[13];
  const float* g_m1 = (const float*)d_in[14];
  const float* be_m1 = (const float*)d_in[15];
  const float* W_m2 = (const float*)d_in[16];
  const float* b_m2 = (const float*)d_in[17];
  const float* g_m2 = (const float*)d_in[18];
  const float* be_m2 = (const float*)d_in[19];
  const float* W_m3 = (const float*)d_in[20];
  const float* b_m3 = (const float*)d_in[21];
  const float* g_m3 = (const float*)d_in[22];
  const float* be_m3 = (const float*)d_in[23];
  const float* W_f = (const float*)d_in[24];
  const float* b_f = (const float*)d_in[25];
  float* out = (float*)d_out;

  const int N = NNODES, E = NEDGES;
  const int* esrc = edge;
  const int* edst = edge + E;

  // workspace layout (floats then ints), all 16B-aligned offsets
  float* ws = (float*)d_ws;
  float* g1 = ws;                              // N*32
  float* mlp1 = g1 + (size_t)N * 32;           // N*64
  float* mlp2 = mlp1 + (size_t)N * 64;         // N*64
  float* mlp3 = mlp2 + (size_t)N * 64;         // N*32
  float* h1 = mlp3 + (size_t)N * 32;           // N*32
  float* g2 = h1 + (size_t)N * 32;             // N*32
  float* h2 = g2 + (size_t)N * 32;             // N*32
  float* s1 = h2 + (size_t)N * 32;             // N
  float* d1 = s1 + N;
  float* s2 = d1 + N;
  float* d2 = s2 + N;
  float* stats = d2 + N;                        // 320 floats (zeroed)
  float* sum1 = stats, *sq1 = stats + 64;
  float* sum2 = stats + 128, *sq2 = stats + 192;
  float* sum3 = stats + 256, *sq3 = stats + 288;
  float* scsh = stats + 320;                    // 320 floats
  float* sc1 = scsh, *sh1 = scsh + 64;
  float* sc2 = scsh + 128, *sh2 = scsh + 192;
  float* sc3 = scsh + 256, *sh3 = scsh + 288;
  int* ip = (int*)(scsh + 320);
  int* deg = ip;            // N
  int* offs = deg + N;      // N
  int* cursor = offs + N;   // N
  int* partial = cursor + N;  // 256
  int* csr = partial + 256;   // E

  hipMemsetAsync(deg, 0, (size_t)N * sizeof(int), stream);
  hipMemsetAsync(stats, 0, 320 * sizeof(float), stream);

  const int NB = (N + 255) / 256;  // 196
  k_hist<<<(E + 255) / 256, 256, 0, stream>>>(edst, deg, E);
  k_scan1<<<NB, 256, 0, stream>>>(deg, offs, partial, N);
  k_scan2<<<1, 256, 0, stream>>>(partial, NB);
  k_scan3<<<NB, 256, 0, stream>>>(offs, cursor, partial, N);
  k_scatter<<<(E + 255) / 256, 256, 0, stream>>>(esrc, edst, cursor, csr, E);

  // fused first layer: x @ [W_m1 | W_g1] -> mlp1 (+b_m1), g1
  k_gemm<256, 32, 96, 6, 64, false><<<(N + 63) / 64, 256, 0, stream>>>(
      x, nullptr, nullptr, W_m1, W_g1, b_m1, mlp1, g1, N);
  k_sdot<<<(N + 7) / 8, 256, 0, stream>>>(g1, as_g1, ad_g1, s1, d1, N);
  k_colstats<64><<<256, 256, 0, stream>>>(mlp1, N, sum1, sq1);
  k_finalize<<<1, 64, 0, stream>>>(sum1, sq1, g_m1, be_m1, sc1, sh1, 64, 1.f / N);
  k_gat_agg<<<(N + 7) / 8, 256, 0, stream>>>(g1, s1, d1, offs, deg, csr, b_g1, h1, N);

  // MLP layer 2: BN1+ReLU(mlp1) @ W_m2 + b_m2
  k_gemm<64, 64, 64, 4, 64, true><<<(N + 63) / 64, 256, 0, stream>>>(
      mlp1, sc1, sh1, W_m2, nullptr, b_m2, mlp2, nullptr, N);
  k_colstats<64><<<256, 256, 0, stream>>>(mlp2, N, sum2, sq2);
  k_finalize<<<1, 64, 0, stream>>>(sum2, sq2, g_m2, be_m2, sc2, sh2, 64, 1.f / N);

  // GAT layer 2
  k_small_gemm_sd<<<(N + 7) / 8, 256, 0, stream>>>(h1, W_g2, as_g2, ad_g2, g2, s2, d2, N);
  k_gat_agg<<<(N + 7) / 8, 256, 0, stream>>>(g2, s2, d2, offs, deg, csr, b_g2, h2, N);

  // MLP layer 3: BN2+ReLU(mlp2) @ W_m3 + b_m3
  k_gemm<64, 64, 32, 2, 32, true><<<(N + 63) / 64, 256, 0, stream>>>(
      mlp2, sc2, sh2, W_m3, nullptr, b_m3, mlp3, nullptr, N);
  k_colstats<32><<<256, 256, 0, stream>>>(mlp3, N, sum3, sq3);
  k_finalize<<<1, 32, 0, stream>>>(sum3, sq3, g_m3, be_m3, sc3, sh3, 32, 1.f / N);

  // final fused epilogue
  k_final<<<N / 16, 256, 0, stream>>>(mlp3, sc3, sh3, h2, W_gf, b_gf, W_f, b_f, out, N);
}